// Round 10
// baseline (53.655 us; speedup 1.0000x reference)
//
#include <hip/hip_runtime.h>
#include <hip/hip_bf16.h>

typedef float fx4 __attribute__((ext_vector_type(4)));
typedef short i16x8 __attribute__((ext_vector_type(8)));
typedef unsigned short u16;

#define NEG_INF_F (-9.0e15f)

__device__ inline u16 f2bf(float v){
  __hip_bfloat16 h = __float2bfloat16(v);
  return *reinterpret_cast<u16*>(&h);
}
__device__ inline unsigned pk2(float lo, float hi){
  return (unsigned)f2bf(lo) | ((unsigned)f2bf(hi) << 16);
}

// ---------------------------------------------------------------------------
// Kernel 1: Wh = x @ W (fp32), f1 = Wh@a1, f2 = Wh@a2 (fp32).
// Wh emitted bf16 in MFMA B-fragment-linear layout whB[bt][kt][ct][lane][8].
// grid (2, 96), 256 threads; thread = one node n.  (~6 us)
// ---------------------------------------------------------------------------
__global__ __launch_bounds__(256) void gat_prep(
    const float* __restrict__ input,   // (8,64,12,512)
    const float* __restrict__ W,       // (64,64)
    const float* __restrict__ Avec,    // (128,1)
    u16*   __restrict__ whB,           // (96,16,4,512) bf16 fragment-linear
    float* __restrict__ f1w,           // (96,512)
    float* __restrict__ f2w)           // (96,512)
{
  __shared__ float Wl[64*64];
  __shared__ float Al[128];
  __shared__ u16   Rp[16384];
  const int tid = threadIdx.x;
  const int bt  = blockIdx.y;
  const int b   = bt / 12, t = bt % 12;
  const int xb  = blockIdx.x;
  const int n   = xb * 256 + tid;

  {
    const fx4* src = (const fx4*)W;
    fx4* dst = (fx4*)Wl;
    #pragma unroll
    for (int i = 0; i < 4; ++i) dst[tid + 256*i] = src[tid + 256*i];
    if (tid < 32) ((fx4*)Al)[tid] = ((const fx4*)Avec)[tid];
  }
  __syncthreads();

  const float* xp = input + ((size_t)b*64*12 + t) * 512 + n;

  fx4 acc[16];
  #pragma unroll
  for (int i = 0; i < 16; ++i) acc[i] = (fx4){0.f,0.f,0.f,0.f};

  #pragma unroll 8
  for (int f = 0; f < 64; ++f) {
    float xv = xp[(size_t)f * 6144];
    const fx4* wr = (const fx4*)(Wl + f*64);
    #pragma unroll
    for (int o4 = 0; o4 < 16; ++o4) acc[o4] += xv * wr[o4];
  }

  float s1 = 0.f, s2 = 0.f;
  #pragma unroll
  for (int o4 = 0; o4 < 16; ++o4) {
    fx4 v  = acc[o4];
    fx4 w1 = ((const fx4*)Al)[o4];
    fx4 w2 = ((const fx4*)Al)[o4 + 16];
    s1 += v[0]*w1[0] + v[1]*w1[1] + v[2]*w1[2] + v[3]*w1[3];
    s2 += v[0]*w2[0] + v[1]*w2[1] + v[2]*w2[2] + v[3]*w2[3];
  }
  f1w[bt*512 + n] = s1;
  f2w[bt*512 + n] = s2;

  const int ktl  = (n >> 5) & 7;
  const int q    = (n >> 3) & 3;
  const int e    = n & 7;
  const int rowb = ktl*2048 + q*128 + e;
  #pragma unroll
  for (int o4 = 0; o4 < 16; ++o4) {
    #pragma unroll
    for (int c = 0; c < 4; ++c) {
      const int o = o4*4 + c;
      Rp[rowb + (o >> 4)*512 + (o & 15)*8] = f2bf(acc[o4][c]);
    }
  }
  __syncthreads();

  uint4* dst = (uint4*)(whB + ((size_t)bt*16 + xb*8) * 2048);
  const uint4* src = (const uint4*)Rp;
  #pragma unroll
  for (int i = 0; i < 8; ++i) dst[tid + 256*i] = src[tid + 256*i];
}

// ---------------------------------------------------------------------------
// Kernel 2 (fused): per-block adj->nibble compress (prologue) + masked
// softmax (R9 max-algebra fast path) + PV via MFMA (+ ones-sums) + ELU.
// grid (32,96), 256 threads (4 waves), 16 rows/block.
// Block reads its own 32KB adj slice with 8 coalesced uint4/lane at entry;
// the 100.7MB adj stream overlaps compute across ~6-7 resident blocks/CU.
// ---------------------------------------------------------------------------
__global__ __launch_bounds__(256, 4) void gat_attn(
    const int*   __restrict__ adj,   // (96,512,512)
    const u16*   __restrict__ whB,   // (96,16,4,512) bf16 fragment-linear
    const float* __restrict__ f1w,
    const float* __restrict__ f2w,
    float*       __restrict__ out)   // (96,512,64)
{
  __shared__ float f1l[16];
  __shared__ float wmaxl[4];
  __shared__ float sums[16];
  __shared__ unsigned char masknib[2048]; // nib g = cols 4g..4g+3 of row g>>7
  __shared__ uint2 lutl[16];
  __shared__ u16   attnl[16*512];    // unnormalized p, bf16, XOR-swizzled

  const int tid = threadIdx.x;
  const int l   = tid & 63;
  const int w   = tid >> 6;
  const int bt  = blockIdx.y;
  const int it  = blockIdx.x;

  // ---- prologue 1: issue the block's 32KB adj slice (8 uint4/lane) -------
  const uint4* adjblk = (const uint4*)(adj + ((size_t)bt*512 + it*16)*512);
  uint4 av[8];
  #pragma unroll
  for (int i = 0; i < 8; ++i) av[i] = adjblk[tid + 256*i];

  // ---- prologue 2 (overlaps the adj latency): f2, f1, LUT ----------------
  const float* f2p = f2w + bt*512;
  const fx4 f20 = ((const fx4*)f2p)[l];        // j = 4l .. 4l+3
  const fx4 f21 = ((const fx4*)f2p)[64 + l];   // j = 256+4l ..
  if (tid < 16) f1l[tid] = f1w[bt*512 + it*16 + tid];
  if (tid < 16) {
    const unsigned nb = tid;
    lutl[tid] = (uint2){ ((nb&1u)?0xFFFFu:0u) | ((nb&2u)?0xFFFF0000u:0u),
                         ((nb&4u)?0xFFFFu:0u) | ((nb&8u)?0xFFFF0000u:0u) };
  }
  float m2 = fmaxf(fmaxf(fmaxf(f20[0], f20[1]), fmaxf(f20[2], f20[3])),
                   fmaxf(fmaxf(f21[0], f21[1]), fmaxf(f21[2], f21[3])));
  #pragma unroll
  for (int off = 32; off >= 1; off >>= 1) m2 = fmaxf(m2, __shfl_xor(m2, off));
  if (l == 0) wmaxl[w] = m2;

  // ---- compress staged adj to nibbles in LDS -----------------------------
  #pragma unroll
  for (int i = 0; i < 8; ++i) {
    unsigned nb = 0u;
    if ((int)av[i].x > 0) nb |= 1u;
    if ((int)av[i].y > 0) nb |= 2u;
    if ((int)av[i].z > 0) nb |= 4u;
    if ((int)av[i].w > 0) nb |= 8u;
    masknib[tid + 256*i] = (unsigned char)nb;
  }
  __syncthreads();
  const float F2max = fmaxf(fmaxf(wmaxl[0], wmaxl[1]), fmaxf(wmaxl[2], wmaxl[3]));

  // factor tables (16 exps, one-time) + underflow-safety bit pattern
  fx4 v0, v1, vh0, vh1;
  #pragma unroll
  for (int c = 0; c < 4; ++c) {
    v0[c]  = __expf(f20[c] - F2max);
    v1[c]  = __expf(f21[c] - F2max);
    vh0[c] = __expf(0.2f*(f20[c] - F2max));
    vh1[c] = __expf(0.2f*(f21[c] - F2max));
  }
  const float thrBig = F2max - 80.f;
  const unsigned big_lo = (f20[0] > thrBig ? 1u : 0u) | (f20[1] > thrBig ? 2u : 0u)
                        | (f20[2] > thrBig ? 4u : 0u) | (f20[3] > thrBig ? 8u : 0u);
  const unsigned big_hi = (f21[0] > thrBig ? 1u : 0u) | (f21[1] > thrBig ? 2u : 0u)
                        | (f21[2] > thrBig ? 4u : 0u) | (f21[3] > thrBig ? 8u : 0u);

  // ---------------- phase A ------------------------------------------------
  const int R0 = w * 4;

  #pragma unroll
  for (int r = 0; r < 4; ++r) {
    const int rowR = R0 + r;
    const unsigned nib0 = masknib[rowR*128 + l];        // cols 4l..4l+3
    const unsigned nib1 = masknib[rowR*128 + 64 + l];   // cols 256+4l..
    const float f1v = f1l[rowR];

    unsigned w0, w1, w2, w3;
    const unsigned sb = (nib0 & big_lo) | (nib1 & big_hi);
    if (__builtin_expect(__any((int)sb), 1)) {
      // fast path: p = max(u*v, uh*vh)  [exact exp/lrelu algebra],
      // masking via bf16-domain AND with nibble->mask LUT
      const float tR = f1v + F2max;
      const float M  = fmaxf(tR, 0.2f*tR);
      const float u  = __expf(tR - M);
      const float uh = __expf(0.2f*tR - M);
      fx4 PA, PB;
      #pragma unroll
      for (int c = 0; c < 4; ++c) {
        PA[c] = fmaxf(u*v0[c], uh*vh0[c]);
        PB[c] = fmaxf(u*v1[c], uh*vh1[c]);
      }
      const uint2 mA = lutl[nib0];
      const uint2 mB = lutl[nib1];
      w0 = pk2(PA[0], PA[1]) & mA.x;
      w1 = pk2(PA[2], PA[3]) & mA.y;
      w2 = pk2(PB[0], PB[1]) & mB.x;
      w3 = pk2(PB[2], PB[3]) & mB.y;
    } else {
      // exact path (rare; also all-masked rows -> uniform p=1)
      float mx = NEG_INF_F;
      mx = fmaxf(mx, (nib0 & 1u) ? f20[0] : NEG_INF_F);
      mx = fmaxf(mx, (nib0 & 2u) ? f20[1] : NEG_INF_F);
      mx = fmaxf(mx, (nib0 & 4u) ? f20[2] : NEG_INF_F);
      mx = fmaxf(mx, (nib0 & 8u) ? f20[3] : NEG_INF_F);
      mx = fmaxf(mx, (nib1 & 1u) ? f21[0] : NEG_INF_F);
      mx = fmaxf(mx, (nib1 & 2u) ? f21[1] : NEG_INF_F);
      mx = fmaxf(mx, (nib1 & 4u) ? f21[2] : NEG_INF_F);
      mx = fmaxf(mx, (nib1 & 8u) ? f21[3] : NEG_INF_F);
      #pragma unroll
      for (int off = 32; off >= 1; off >>= 1) mx = fmaxf(mx, __shfl_xor(mx, off));
      const float tM = f1v + mx;
      const float Mc = fmaxf(tM, 0.2f*tM);
      const float Mf = (mx == NEG_INF_F) ? NEG_INF_F : Mc;
      float pv[8];
#define GAT_S(idx, bb_, ff) { float s = f1v + (ff); float lr = fmaxf(s, 0.2f*s); \
      float ee = (bb_) ? lr : NEG_INF_F; pv[idx] = __expf(ee - Mf); }
      GAT_S(0, nib0 & 1u, f20[0]) GAT_S(1, nib0 & 2u, f20[1])
      GAT_S(2, nib0 & 4u, f20[2]) GAT_S(3, nib0 & 8u, f20[3])
      GAT_S(4, nib1 & 1u, f21[0]) GAT_S(5, nib1 & 2u, f21[1])
      GAT_S(6, nib1 & 4u, f21[2]) GAT_S(7, nib1 & 8u, f21[3])
#undef GAT_S
      w0 = pk2(pv[0], pv[1]); w1 = pk2(pv[2], pv[3]);
      w2 = pk2(pv[4], pv[5]); w3 = pk2(pv[6], pv[7]);
    }

    const unsigned swz = (unsigned)((rowR & 7) << 4);
    char* base = (char*)attnl + rowR * 1024;
    *(uint2*)(base + (((unsigned)(      8*l)) ^ swz)) = (uint2){w0, w1};
    *(uint2*)(base + (((unsigned)(512 + 8*l)) ^ swz)) = (uint2){w2, w3};
  }
  __syncthreads();

  // ---------------- phase B: MFMA PV (+ ones-sums on wave 0) --------------
  const int r = l & 15, q = l >> 4;
  const unsigned swzB = (unsigned)((r & 7) << 4);
  const char* aBase = (const char*)attnl + r * 1024;
  const u16*  wp    = whB + (size_t)bt*32768 + w*512 + l*8;
  i16x8 bones;
  #pragma unroll
  for (int e = 0; e < 8; ++e) bones[e] = (short)0x3F80;  // bf16 1.0
  fx4 acc = {0,0,0,0}, accS = {0,0,0,0};

  #pragma unroll
  for (int kt = 0; kt < 16; ++kt) {
    i16x8 af = *(const i16x8*)(aBase + (((unsigned)(kt*64 + q*16)) ^ swzB));
    i16x8 bf = *(const i16x8*)(wp + kt*2048);
    acc = __builtin_amdgcn_mfma_f32_16x16x32_bf16(af, bf, acc, 0, 0, 0);
    if (w == 0)
      accS = __builtin_amdgcn_mfma_f32_16x16x32_bf16(af, bones, accS, 0, 0, 0);
  }
  if (w == 0 && r == 0) {
    #pragma unroll
    for (int rr = 0; rr < 4; ++rr) sums[q*4 + rr] = accS[rr];
  }
  __syncthreads();

  // epilogue: normalize + ELU.  C/D layout: col = l&15, row = q*4 + rr
  float* op = out + ((size_t)bt*512 + it*16) * 64;
  #pragma unroll
  for (int rr = 0; rr < 4; ++rr) {
    const float rs = 1.0f / sums[q*4 + rr];
    float v = acc[rr] * rs;
    v = v > 0.f ? v : expm1f(v);
    op[(q*4 + rr)*64 + w*16 + r] = v;
  }
}

// ---------------------------------------------------------------------------
extern "C" void kernel_launch(void* const* d_in, const int* in_sizes, int n_in,
                              void* d_out, int out_size, void* d_ws, size_t ws_size,
                              hipStream_t stream) {
  const float* input = (const float*)d_in[0];   // (8,64,12,512) f32
  const int*   adj   = (const int*)  d_in[1];   // (8,12,512,512) i32
  const float* W     = (const float*)d_in[2];   // (64,64) f32
  const float* Avec  = (const float*)d_in[3];   // (128,1) f32
  float* out = (float*)d_out;

  // ws: whB bf16 (6,291,456 B) | f1 (196,608) | f2 (196,608)
  char* ws = (char*)d_ws;
  u16*   whB = (u16*)ws;
  float* f1w = (float*)(ws + 6291456);
  float* f2w = (float*)(ws + 6291456 + 196608);

  gat_prep<<<dim3(2, 96), 256, 0, stream>>>(input, W, Avec, whB, f1w, f2w);
  gat_attn<<<dim3(32, 96), 256, 0, stream>>>(adj, whB, f1w, f2w, out);
}